// Round 3
// baseline (190.892 us; speedup 1.0000x reference)
//
#include <hip/hip_runtime.h>
#include <hip/hip_bf16.h>
#include <math.h>

typedef __attribute__((ext_vector_type(8))) short short8;
typedef __attribute__((ext_vector_type(4))) float f32x4;

// ---------------- workspace layout ----------------
// ushort region (bf16 data), element offsets:
#define US_XP    0
#define N_XP     (8*60*60*64)            // padded NHWC x, pad=2, bf16
#define US_WOFF  (US_XP + N_XP)          // offset-conv weights, A-frag order
#define N_WOFF   (25*2*8*64*8)
#define US_W5    (US_WOFF + N_WOFF)      // w5 + sub tap (26 taps)
#define N_W5     (26*2*8*64*8)
#define US_W3    (US_W5 + N_W5)          // w3 + sub tap (10 taps)
#define N_W3     (10*2*8*64*8)
#define US_TOT   (US_W3 + N_W3)
// float region, 16B-aligned after ushort region:
#define FB_BYTES (((US_TOT*2) + 15) & ~15)
#define F_BOM    0                       // offset-conv bias (128, padded)
#define F_B5     128                     // b5 + sub_b
#define F_B3     256                     // b3 + sub_b
#define F_OM     384                     // offset maps (8,128,3136) fp32
#define N_OM     (8*128*3136)
#define N_ITEMS  (8*34*3136)             // bilinear meta items (25 k5 + 9 k3 taps)
#define F_OFFS   (F_OM + N_OM)           // int4 per item (4 corner byte offsets)
#define F_WTS    (F_OFFS + N_ITEMS*4)    // uint2 per item (4 bf16 weights)

__device__ __forceinline__ unsigned short f2bf(float f) {
    union { float f; unsigned u; } v; v.f = f;
    unsigned r = v.u + 0x7FFFu + ((v.u >> 16) & 1u);
    return (unsigned short)(r >> 16);
}
__device__ __forceinline__ unsigned pack2(float lo, float hi) {
    __hip_bfloat162 h = __float22bfloat162_rn(make_float2(lo, hi));
    return *(unsigned*)&h;
}
__device__ __forceinline__ unsigned blend2(unsigned a, unsigned b, unsigned c, unsigned d,
                                           float w00, float w01, float w10, float w11) {
    float lo = __uint_as_float(a << 16) * w00 + __uint_as_float(b << 16) * w01
             + __uint_as_float(c << 16) * w10 + __uint_as_float(d << 16) * w11;
    float hi = __uint_as_float(a & 0xffff0000u) * w00 + __uint_as_float(b & 0xffff0000u) * w01
             + __uint_as_float(c & 0xffff0000u) * w10 + __uint_as_float(d & 0xffff0000u) * w11;
    return pack2(lo, hi);
}

// ---------------- prep: pad x (bf16 NHWC) + pack weights into A-frag order ----------------
// A-frag (16x16x32 bf16): lane l holds A[oc = l&15][c = (l>>4)*8 + j], j=0..7.
// Packed index: ((((tap*2 + kt)*8 + oct)*64 + lane)*8 + j)
__global__ __launch_bounds__(256) void prep_kernel(
    const float* __restrict__ x,
    const float* __restrict__ w3, const float* __restrict__ b3,
    const float* __restrict__ off3w, const float* __restrict__ off3b,
    const float* __restrict__ w5, const float* __restrict__ b5,
    const float* __restrict__ off5w, const float* __restrict__ off5b,
    const float* __restrict__ subw, const float* __restrict__ subb,
    unsigned short* __restrict__ us, float* __restrict__ fb)
{
    const int NTOT = US_TOT + 384;
    for (int i = blockIdx.x*256 + threadIdx.x; i < NTOT; i += gridDim.x*256) {
        if (i < US_TOT) {
            float v = 0.f;
            if (i < US_WOFF) {                      // padded bf16 NHWC x
                int c = i & 63, t = i >> 6;
                int xx = t % 60; t /= 60;
                int yy = t % 60; int b = t / 60;
                int y = yy - 2, xc = xx - 2;
                if ((unsigned)y < 56u && (unsigned)xc < 56u)
                    v = x[((b*64 + c)*56 + y)*56 + xc];
            } else {
                int j, mode;
                if (i < US_W5)      { j = i - US_WOFF; mode = 0; }
                else if (i < US_W3) { j = i - US_W5;   mode = 1; }
                else                { j = i - US_W3;   mode = 2; }
                int j8   = j & 7;
                int lane = (j >> 3) & 63;
                int oct  = (j >> 9) & 7;
                int kt   = (j >> 12) & 1;
                int tap  = j >> 13;
                int oc   = oct*16 + (lane & 15);
                int c    = kt*32 + (lane >> 4)*8 + j8;
                if (mode == 0) {                    // offset conv (5x5, k3 embedded center)
                    if (oc < 27) {
                        int ky = tap/5, kx = tap%5;
                        if (ky>=1 && ky<=3 && kx>=1 && kx<=3)
                            v = off3w[((oc*64 + c)*3 + (ky-1))*3 + (kx-1)];
                    } else if (oc < 102) {
                        v = off5w[((oc-27)*64 + c)*25 + tap];
                    }
                } else if (mode == 1) {             // w5 (25) + sub tap
                    v = (tap < 25) ? w5[(oc*64 + c)*25 + tap] : subw[oc*64 + c];
                } else {                            // w3 (9) + sub tap
                    v = (tap < 9) ? w3[(oc*64 + c)*9 + tap] : subw[oc*64 + c];
                }
            }
            us[i] = f2bf(v);
        } else {
            int fj = i - US_TOT;
            float v;
            if (fj < 128)      v = (fj < 27) ? off3b[fj] : ((fj < 102) ? off5b[fj-27] : 0.f);
            else if (fj < 256) { int o = fj-128; v = b5[o] + subb[o]; }
            else               { int o = fj-256; v = b3[o] + subb[o]; }
            fb[fj] = v;
        }
    }
}

// ---------------- meta: per (b, tap, px) bilinear corner offsets + weights ----------------
__global__ __launch_bounds__(256) void meta_kernel(
    const float* __restrict__ om, int4* __restrict__ offs, uint2* __restrict__ wts)
{
    const int idx = blockIdx.x*256 + threadIdx.x;      // grid sized exactly
    const int pix = idx % 3136;
    const int r   = idx / 3136;
    const int t   = r % 34;
    const int b   = r / 34;
    int ky, kx, cdy, cdx, cml, HP, SH;
    if (t < 25) { ky = t/5;  kx = t%5;  cdy = 27+t; cdx = 52+t; cml = 77+t; HP = 60; SH = 0; }
    else { int tt = t-25; ky = tt/3; kx = tt%3; cdy = tt; cdx = 9+tt; cml = 18+tt; HP = 58; SH = 1; }
    const int oy = pix/56, ox = pix - oy*56;
    const size_t base = (size_t)b*128*3136 + pix;
    const float dy = om[base + (size_t)cdy*3136];
    const float dx = om[base + (size_t)cdx*3136];
    const float ml = om[base + (size_t)cml*3136];
    const float mask = 1.f / (1.f + __expf(-ml));
    const float py = (float)(oy + ky) + dy;
    const float qx = (float)(ox + kx) + dx;
    const float y0f = floorf(py), x0f = floorf(qx);
    const float ty = py - y0f, tx = qx - x0f;
    const int y0 = (int)y0f, x0 = (int)x0f, y1 = y0+1, x1 = x0+1;
    float w00 = (1.f-ty)*(1.f-tx)*mask;
    float w01 = (1.f-ty)*tx*mask;
    float w10 = ty*(1.f-tx)*mask;
    float w11 = ty*tx*mask;
    const bool vy0 = (unsigned)y0 < (unsigned)HP, vy1 = (unsigned)y1 < (unsigned)HP;
    const bool vx0 = (unsigned)x0 < (unsigned)HP, vx1 = (unsigned)x1 < (unsigned)HP;
    if (!(vy0 && vx0)) w00 = 0.f;
    if (!(vy0 && vx1)) w01 = 0.f;
    if (!(vy1 && vx0)) w10 = 0.f;
    if (!(vy1 && vx1)) w11 = 0.f;
    const int yc0 = min(max(y0,0),HP-1)+SH, yc1 = min(max(y1,0),HP-1)+SH;
    const int xc0 = min(max(x0,0),HP-1)+SH, xc1 = min(max(x1,0),HP-1)+SH;
    offs[idx] = make_int4((yc0*60+xc0)<<7, (yc0*60+xc1)<<7, (yc1*60+xc0)<<7, (yc1*60+xc1)<<7);
    wts[idx]  = make_uint2(pack2(w00,w01), pack2(w10,w11));
}

// ---------------- MFMA conv: PXT px x 128 oc per block ----------------
// Wave w owns octiles {2w, 2w+1} over all PXT px. Per tap: stage cols[px][c] bf16
// (double-buffered, 1 barrier/tap, b128 writes, 8ch/lane), then 16x16x32 MFMAs.
template<int PXT, bool DEFORM>
__global__ __launch_bounds__(256, 3) void convm(
    const unsigned short* __restrict__ xp,   // bf16 (B,60,60,64)
    const int4* __restrict__ offs, const uint2* __restrict__ wts,
    float* __restrict__ out,
    const unsigned short* __restrict__ wpA, const float* __restrict__ biasA,
    const unsigned short* __restrict__ wpB, const float* __restrict__ biasB,
    int ntA, int ntB, int k2A, int k2B, int tofsA, int tofsB,
    int outc0A, int outc0B, int out_cs)
{
    const int kind  = DEFORM ? (int)(blockIdx.x & 1) : 0;
    const int pxblk = DEFORM ? (int)(blockIdx.x >> 1) : (int)blockIdx.x;
    const unsigned short* wp = kind ? wpB : wpA;
    const float* bias = kind ? biasB : biasA;
    const int ntaps = kind ? ntB : ntA;
    const int K2    = kind ? k2B : k2A;
    const int tofs  = kind ? tofsB : tofsA;
    const int outc0 = kind ? outc0B : outc0A;

    const int b    = blockIdx.y;
    const int pix0 = pxblk * PXT;
    const int lane = threadIdx.x & 63;
    const int wave = threadIdx.x >> 6;
    const int r15 = lane & 15, q4 = lane >> 4;
    const int cg  = lane & 7,  pr = lane >> 3;

    constexpr int NIT = PXT / 32;     // stage iterations (8 px x 8 chgroups / wave / it)
    constexpr int NPT = PXT / 16;     // px tiles per wave in GEMM

    __shared__ unsigned short cols[2][PXT*72];  // [px][c], stride 72 (144 B)

    f32x4 acc[2][NPT];
#pragma unroll
    for (int i = 0; i < 2; ++i)
#pragma unroll
        for (int pt = 0; pt < NPT; ++pt) acc[i][pt] = (f32x4){0.f,0.f,0.f,0.f};

    const unsigned short* xpb = xp + (size_t)b*(60*60*64);
    const char* xb = (const char*)xpb;

    int coff[NIT], mbase[NIT];
#pragma unroll
    for (int it = 0; it < NIT; ++it) {
        const int px  = wave*(NIT*8) + it*8 + pr;
        const int pix = pix0 + px;
        const int oy  = pix/56, ox = pix - oy*56;
        coff[it]  = (((oy+2)*60) + ox + 2) << 7;         // center (sub-conv) byte offset
        mbase[it] = (b*34 + tofs)*3136 + pix;
    }

    auto stage = [&](int tap, unsigned short* buf) {
        int koff = 0;
        if (!DEFORM) { int ky = tap/5, kx = tap - ky*5; koff = ((ky-2)*60 + (kx-2)) << 7; }
#pragma unroll
        for (int it = 0; it < NIT; ++it) {
            const int px = wave*(NIT*8) + it*8 + pr;
            uint4 res;
            if (!DEFORM) {
                res = *(const uint4*)(xb + coff[it] + koff + cg*16);
            } else if (tap >= K2) {                       // fused 1x1 sub-conv tap
                res = *(const uint4*)(xb + coff[it] + cg*16);
            } else {
                const int mi = mbase[it] + tap*3136;
                const int4 o4 = offs[mi];
                const uint2 wq = wts[mi];
                const float w00 = __uint_as_float(wq.x << 16);
                const float w01 = __uint_as_float(wq.x & 0xffff0000u);
                const float w10 = __uint_as_float(wq.y << 16);
                const float w11 = __uint_as_float(wq.y & 0xffff0000u);
                const uint4 qa = *(const uint4*)(xb + o4.x + cg*16);
                const uint4 qb = *(const uint4*)(xb + o4.y + cg*16);
                const uint4 qc = *(const uint4*)(xb + o4.z + cg*16);
                const uint4 qd = *(const uint4*)(xb + o4.w + cg*16);
                res.x = blend2(qa.x, qb.x, qc.x, qd.x, w00, w01, w10, w11);
                res.y = blend2(qa.y, qb.y, qc.y, qd.y, w00, w01, w10, w11);
                res.z = blend2(qa.z, qb.z, qc.z, qd.z, w00, w01, w10, w11);
                res.w = blend2(qa.w, qb.w, qc.w, qd.w, w00, w01, w10, w11);
            }
            *(uint4*)&buf[px*72 + cg*8] = res;            // 16B-aligned (px*144 + cg*16)
        }
    };

    auto gemm = [&](int tap, const unsigned short* buf) {
#pragma unroll
        for (int kt = 0; kt < 2; ++kt) {
            short8 Af[2];
#pragma unroll
            for (int i = 0; i < 2; ++i)
                Af[i] = *(const short8*)(wp + ((size_t)((tap*2+kt)*8 + wave*2 + i)*64 + lane)*8);
#pragma unroll
            for (int pt = 0; pt < NPT; ++pt) {
                short8 Bf = *(const short8*)(buf + (pt*16 + r15)*72 + kt*32 + q4*8);
#pragma unroll
                for (int i = 0; i < 2; ++i)
                    acc[i][pt] = __builtin_amdgcn_mfma_f32_16x16x32_bf16(Af[i], Bf, acc[i][pt], 0, 0, 0);
            }
        }
    };

    stage(0, cols[0]);
    __syncthreads();
    for (int t = 0; t < ntaps; ++t) {
        if (t + 1 < ntaps) stage(t + 1, cols[(t+1) & 1]);
        gemm(t, cols[t & 1]);
        __syncthreads();
    }

    // epilogue: D row=(lane>>4)*4+reg (oc), col=lane&15 (px)
#pragma unroll
    for (int i = 0; i < 2; ++i)
#pragma unroll
    for (int pt = 0; pt < NPT; ++pt)
#pragma unroll
    for (int reg = 0; reg < 4; ++reg) {
        const int oc  = (wave*2 + i)*16 + q4*4 + reg;
        const int pix = pix0 + pt*16 + r15;
        float v = acc[i][pt][reg] + bias[oc];
        if (DEFORM) v = fmaxf(v, 0.f);
        out[((size_t)b*out_cs + outc0 + oc)*3136 + pix] = v;
    }
}

// ---------------- launch ----------------
extern "C" void kernel_launch(void* const* d_in, const int* in_sizes, int n_in,
                              void* d_out, int out_size, void* d_ws, size_t ws_size,
                              hipStream_t stream)
{
    (void)in_sizes; (void)n_in; (void)out_size; (void)ws_size;
    const float* x     = (const float*)d_in[0];
    const float* w3    = (const float*)d_in[1];
    const float* b3    = (const float*)d_in[2];
    const float* off3w = (const float*)d_in[3];
    const float* off3b = (const float*)d_in[4];
    const float* w5    = (const float*)d_in[5];
    const float* b5    = (const float*)d_in[6];
    const float* off5w = (const float*)d_in[7];
    const float* off5b = (const float*)d_in[8];
    const float* subw  = (const float*)d_in[9];
    const float* subb  = (const float*)d_in[10];

    unsigned short* us = (unsigned short*)d_ws;
    float* fb   = (float*)((char*)d_ws + FB_BYTES);
    float* omb  = fb + F_OM;
    int4*  offs = (int4*)(fb + F_OFFS);
    uint2* wts  = (uint2*)(fb + F_WTS);
    float* out  = (float*)d_out;

    prep_kernel<<<dim3(1024), dim3(256), 0, stream>>>(
        x, w3, b3, off3w, off3b, w5, b5, off5w, off5b, subw, subb, us, fb);

    // offset conv (k3 embedded in 5x5, 102ch padded to 128) -> om buffer
    convm<32, false><<<dim3(98, 8), dim3(256), 0, stream>>>(
        us + US_XP, nullptr, nullptr, omb,
        us + US_WOFF, fb + F_BOM, us + US_WOFF, fb + F_BOM,
        25, 25, 25, 25, 0, 0, 0, 0, 128);

    // bilinear meta precompute (one item per (b, tap34, px))
    meta_kernel<<<dim3(N_ITEMS/256), dim3(256), 0, stream>>>(omb, offs, wts);

    // deform convs + fused sub tap + bias + relu; even blocks k5, odd blocks k3
    convm<64, true><<<dim3(98, 8), dim3(256), 0, stream>>>(
        us + US_XP, offs, wts, out,
        us + US_W5, fb + F_B5, us + US_W3, fb + F_B3,
        26, 10, 25, 9, 0, 25, 128, 0, 256);
}